// Round 6
// baseline (213.915 us; speedup 1.0000x reference)
//
#include <hip/hip_runtime.h>

// LabelGenerator: masks [32,1,768,768] f32 in {0,1}
//  out0 = 35x35 box mean (SAME, zero pad)      -> f32 [32,768,768]
//  out1 = pfm: mask?1 : (31x31 dilation?0 : 2) -> f32 values 0/1/2
// Fused single kernel, bit-packed. R6: 768 threads/block = 4 row-groups x
// (192 col-threads x 4 cols) -> float4 stores (perfect coalescing), all
// threads active, 24 waves/CU.
// Dilation on a 0/1 mask == (31x31 box sum >= 1).

#define BATCH 32
#define HH 768
#define WW 768
#define NPIX (HH * WW)

constexpr int TYO  = 48;               // output rows per block
constexpr int HALO = 17;               // 35//2
constexpr int ROWS = TYO + 2 * HALO;   // 82 staged rows
constexpr int NSEG = 12;               // 768/64 u64 segments per row
constexpr int SSEG = NSEG + 2;         // +2 zero-pad segments
constexpr int NT   = 768;              // threads per block (12 waves)
constexpr int NG   = 4;                // row groups
constexpr int RPG  = TYO / NG;         // 12 output rows per group
constexpr int CT   = 192;              // col-threads per group
constexpr int CPT  = 4;                // cols per thread (192*4 = 768)

__global__ __launch_bounds__(NT)
void label_gen_fused(const float* __restrict__ in, float* __restrict__ out) {
    __shared__ unsigned long long sbits[ROWS][SSEG];   // 82*14*8 = 9184 B

    const int tid  = threadIdx.x;
    const int lane = tid & 63;
    const int wv   = tid >> 6;          // 0..11
    const int y0   = blockIdx.x * TYO;
    const int b    = blockIdx.y;
    const float* __restrict__ src = in + (size_t)b * NPIX;

    // ---- Phase A: global f32 -> LDS bit rows (ballot pack), 12 waves ----
    for (int lr = wv; lr < ROWS; lr += 12) {
        const int r = y0 - HALO + lr;
        unsigned long long bb[NSEG];
        if ((unsigned)r < (unsigned)HH) {          // wave-uniform branch
            const float* rp = src + (size_t)r * WW;
            #pragma unroll
            for (int j = 0; j < NSEG; ++j)
                bb[j] = __ballot(rp[64 * j + lane] > 0.5f);
        } else {
            #pragma unroll
            for (int j = 0; j < NSEG; ++j) bb[j] = 0ull;
        }
        if (lane == 0) {
            sbits[lr][0] = 0ull;
            #pragma unroll
            for (int j = 0; j < NSEG; ++j) sbits[lr][j + 1] = bb[j];
            sbits[lr][SSEG - 1] = 0ull;
        }
    }
    __syncthreads();

    // ---- Phase B: 4 groups x 192 col-threads x 4 cols ----
    const int g   = tid / CT;           // 0..3
    const int ct  = tid - g * CT;       // 0..191
    const int c0  = CPT * ct;           // 0,4,...,764
    const int yb  = y0 + RPG * g;       // group's first output row
    const int lr0 = RPG * g;            // LDS row of image row yb-17
    const int s   = c0 - HALO;
    const int q   = (s >> 6) + 1;       // padded u64 index (arith shift, s<0 ok)
    const int sh  = s & 63;             // 4ct-17 odd -> never 0

    auto win = [&](int lr) -> unsigned long long {
        return (sbits[lr][q] >> sh) | (sbits[lr][q + 1] << (64 - sh));
    };
    const unsigned long long M35 = (1ull << 35) - 1;
    const unsigned long long M31 = (1ull << 31) - 1;
    auto bit = [](unsigned long long w, int k) -> int { return (int)((w >> k) & 1ull); };

    // H35 for cols c0..c0+3 (w bit j = mask col c0-17+j), packed 4x16-bit
    auto h35swar = [&](unsigned long long w) -> uint2 {
        const int h0 = (int)__popcll(w & M35);
        const int h1 = h0 + bit(w, 35) - bit(w, 0);
        const int h2 = h1 + bit(w, 36) - bit(w, 1);
        const int h3 = h2 + bit(w, 37) - bit(w, 2);
        return make_uint2((unsigned)(h0 | (h1 << 16)), (unsigned)(h2 | (h3 << 16)));
    };
    auto h31swar = [&](unsigned long long w) -> uint2 {
        const int d0 = (int)__popcll((w >> 2) & M31);
        const int d1 = d0 + bit(w, 33) - bit(w, 2);
        const int d2 = d1 + bit(w, 34) - bit(w, 3);
        const int d3 = d2 + bit(w, 35) - bit(w, 4);
        return make_uint2((unsigned)(d0 | (d1 << 16)), (unsigned)(d2 | (d3 << 16)));
    };

    // init vertical sums at y = yb (LDS rows lr0 .. lr0+34)
    uint2 v35 = make_uint2(0u, 0u), v31 = make_uint2(0u, 0u);
    #pragma unroll
    for (int k = 0; k < 35; ++k) {
        const unsigned long long w = win(lr0 + k);
        const uint2 a = h35swar(w);
        v35.x += a.x; v35.y += a.y;
        if (k >= 2 && k <= 32) {
            const uint2 d = h31swar(w);
            v31.x += d.x; v31.y += d.y;
        }
    }

    float* orow = out + (size_t)b * NPIX + (size_t)yb * WW + c0;
    float* prow = orow + (size_t)BATCH * NPIX;

    for (int i = 0; i < RPG; ++i) {
        const int lr = lr0 + HALO + i;           // LDS row of output row yb+i
        const unsigned long long mwin = win(lr); // mask col c0+k = bit 17+k

        float4 r4, p4;
        r4.x = (float)(v35.x & 0xFFFFu) * (1.0f / 1225.0f);
        r4.y = (float)(v35.x >> 16)     * (1.0f / 1225.0f);
        r4.z = (float)(v35.y & 0xFFFFu) * (1.0f / 1225.0f);
        r4.w = (float)(v35.y >> 16)     * (1.0f / 1225.0f);
        p4.x = bit(mwin, 17) ? 1.0f : ((v31.x & 0xFFFFu) ? 0.0f : 2.0f);
        p4.y = bit(mwin, 18) ? 1.0f : ((v31.x >> 16)     ? 0.0f : 2.0f);
        p4.z = bit(mwin, 19) ? 1.0f : ((v31.y & 0xFFFFu) ? 0.0f : 2.0f);
        p4.w = bit(mwin, 20) ? 1.0f : ((v31.y >> 16)     ? 0.0f : 2.0f);

        *(float4*)orow = r4;
        *(float4*)prow = p4;
        orow += WW; prow += WW;

        if (i < RPG - 1) {
            // slide: v35 += H35(y+18) - H35(y-17); v31 += H31(y+16) - H31(y-15)
            const uint2 e35 = h35swar(win(lr + 18));
            const uint2 l35 = h35swar(win(lr - 17));
            const uint2 e31 = h31swar(win(lr + 16));
            const uint2 l31 = h31swar(win(lr - 15));
            // per-field: 0 <= value <= 1225+35 < 2^16 -> SWAR-safe
            v35.x = v35.x + e35.x - l35.x;  v35.y = v35.y + e35.y - l35.y;
            v31.x = v31.x + e31.x - l31.x;  v31.y = v31.y + e31.y - l31.y;
        }
    }
}

extern "C" void kernel_launch(void* const* d_in, const int* in_sizes, int n_in,
                              void* d_out, int out_size, void* d_ws, size_t ws_size,
                              hipStream_t stream) {
    const float* masks = (const float*)d_in[0];
    float* out = (float*)d_out;
    dim3 grid(HH / TYO, BATCH);    // 16 x 32 = 512 blocks, 2 per CU
    label_gen_fused<<<grid, NT, 0, stream>>>(masks, out);
}

// Round 7
// 211.824 us; speedup vs baseline: 1.0099x; 1.0099x over previous
//
#include <hip/hip_runtime.h>

// LabelGenerator: masks [32,1,768,768] f32 in {0,1}
//  out0 = 35x35 box mean (SAME, zero pad)      -> f32 [32,768,768]
//  out1 = pfm: mask?1 : (31x31 dilation?0 : 2) -> f32 values 0/1/2
// R7: three-phase fused kernel.
//  A: ballot-pack 82 mask rows into LDS bit rows (12 u64 + zero pads).
//  H: each row evaluated ONCE per 4-col group: h35 via popcount+1-bit slides,
//     31-wide OR via log-step smear; packed one byte/col
//     (h35 | mask<<6 | or31<<7) into a 63 KB LDS h-map.
//  B: vertical sliding sums on packed bytes: v35 as 2x(2x16-bit) SWAR,
//     dilation as 4x8-bit SWAR count of or-flags (==0 <=> outside dilation);
//     3 ds_read_b32 + ~20 VALU per output row (ring-2 caches for e31/l35).
// Dilation on a 0/1 mask == (31x31 box sum >= 1).

#define BATCH 32
#define HH 768
#define WW 768
#define NPIX (HH * WW)

constexpr int TYO  = 48;               // output rows per block
constexpr int HALO = 17;               // 35//2
constexpr int ROWS = TYO + 2 * HALO;   // 82 staged rows
constexpr int NSEG = 12;               // 768/64 u64 segments per row
constexpr int SSEG = NSEG + 2;         // +2 zero-pad segments
constexpr int NT   = 768;              // threads per block (12 waves)
constexpr int NG   = 4;                // row groups
constexpr int RPG  = TYO / NG;         // 12 output rows per group
constexpr int CT   = 192;              // col-threads per group (x4 cols)

__global__ __launch_bounds__(NT)
void label_gen_fused(const float* __restrict__ in, float* __restrict__ out) {
    __shared__ unsigned long long sbits[ROWS][SSEG];   // 9184 B
    __shared__ unsigned int hm[ROWS][CT];              // 62976 B: 4 packed bytes/u32

    const int tid  = threadIdx.x;
    const int lane = tid & 63;
    const int wv   = tid >> 6;          // 0..11
    const int y0   = blockIdx.x * TYO;
    const int b    = blockIdx.y;
    const float* __restrict__ src = in + (size_t)b * NPIX;

    // ---- Phase A: global f32 -> LDS bit rows (ballot pack) ----
    for (int lr = wv; lr < ROWS; lr += NT / 64) {
        const int r = y0 - HALO + lr;
        unsigned long long bb[NSEG];
        if ((unsigned)r < (unsigned)HH) {          // wave-uniform branch
            const float* rp = src + (size_t)r * WW;
            #pragma unroll
            for (int j = 0; j < NSEG; ++j)
                bb[j] = __ballot(rp[64 * j + lane] > 0.5f);
        } else {
            #pragma unroll
            for (int j = 0; j < NSEG; ++j) bb[j] = 0ull;
        }
        if (lane == 0) {
            sbits[lr][0] = 0ull;
            #pragma unroll
            for (int j = 0; j < NSEG; ++j) sbits[lr][j + 1] = bb[j];
            sbits[lr][SSEG - 1] = 0ull;
        }
    }
    __syncthreads();

    // ---- Phase H: per-row horizontal values, each row evaluated once ----
    {
        const int r0 = tid / CT;            // 0..3
        const int ct = tid - r0 * CT;       // 0..191
        const int c0 = 4 * ct;
        const int s  = c0 - HALO;
        const int q  = (s >> 6) + 1;        // padded u64 index (arith shift)
        const int sh = s & 63;              // odd -> never 0
        const unsigned long long M35 = (1ull << 35) - 1;
        for (int lr = r0; lr < ROWS; lr += NG) {
            // win bit j = mask col c0-17+j
            const unsigned long long w =
                (sbits[lr][q] >> sh) | (sbits[lr][q + 1] << (64 - sh));
            const int h0 = (int)__popcll(w & M35);
            const int h1 = h0 + (int)((w >> 35) & 1) - (int)(w & 1);
            const int h2 = h1 + (int)((w >> 36) & 1) - (int)((w >> 1) & 1);
            const int h3 = h2 + (int)((w >> 37) & 1) - (int)((w >> 2) & 1);
            // 16-smear: sm bit k = OR of w bits k..k+15
            unsigned long long sm = w | (w >> 1);
            sm |= sm >> 2; sm |= sm >> 4; sm |= sm >> 8;
            // or31 for col c0+j = OR of w bits (j+2)..(j+32) = sm[j+2]|sm[j+17]
            const unsigned int o4 = (unsigned int)(((sm >> 2) | (sm >> 17)) & 0xFull);
            const unsigned int m4 = (unsigned int)((w >> 17) & 0xFull);
            const unsigned int mb =
                (((m4 & 1u) | ((m4 & 2u) << 7) | ((m4 & 4u) << 14) | ((m4 & 8u) << 21)) << 6);
            const unsigned int ob =
                (((o4 & 1u) | ((o4 & 2u) << 7) | ((o4 & 4u) << 14) | ((o4 & 8u) << 21)) << 7);
            hm[lr][ct] = (unsigned)h0 | ((unsigned)h1 << 8) | ((unsigned)h2 << 16)
                       | ((unsigned)h3 << 24) | mb | ob;
        }
    }
    __syncthreads();

    // ---- Phase B: vertical SWAR sliding sums over packed bytes ----
    const int g   = tid / CT;           // 0..3
    const int ct  = tid - g * CT;       // 0..191
    const int c0  = 4 * ct;
    const int yb  = y0 + RPG * g;       // group's first output row
    const int lr0 = RPG * g;            // LDS row of image row yb-17

    const unsigned int M6 = 0x003F003Fu;   // 6-bit h fields of bytes (0,2)/(1,3)
    const unsigned int M1 = 0x01010101u;   // or-flag per byte

    unsigned int vA = 0, vB = 0;   // 2x16-bit fields: cols (0,2) and (1,3)
    unsigned int c31 = 0;          // 4x8-bit or-flag counts per col
    unsigned int ring_e[2], ring_l[2];
    #pragma unroll
    for (int k = 0; k < 35; ++k) {
        const unsigned int x = hm[lr0 + k][ct];
        vA += x & M6;
        vB += (x >> 8) & M6;
        if (k >= 2 && k <= 32) c31 += (x >> 7) & M1;
        if (k == 0)  ring_l[0] = x;    // row lr0+0 (l35 at i=0)
        if (k == 1)  ring_l[1] = x;    // row lr0+1 (l35 at i=1)
        if (k == 33) ring_e[0] = x;    // row lr0+33 (e31 at i=0)
        if (k == 34) ring_e[1] = x;    // row lr0+34 (e31 at i=1)
    }

    float* orow = out + (size_t)b * NPIX + (size_t)yb * WW + c0;
    float* prow = orow + (size_t)BATCH * NPIX;

    for (int i = 0; i < RPG; ++i) {
        const int lr = lr0 + HALO + i;         // LDS row of output row yb+i
        const unsigned int xc = hm[lr][ct];    // center row (mask bits)

        float4 r4, p4;
        r4.x = (float)(vA & 0xFFFFu) * (1.0f / 1225.0f);
        r4.y = (float)(vB & 0xFFFFu) * (1.0f / 1225.0f);
        r4.z = (float)(vA >> 16)     * (1.0f / 1225.0f);
        r4.w = (float)(vB >> 16)     * (1.0f / 1225.0f);
        p4.x = ((xc >> 6) & 1u)  ? 1.0f : ((c31 & 0xFFu)         ? 0.0f : 2.0f);
        p4.y = ((xc >> 14) & 1u) ? 1.0f : (((c31 >> 8) & 0xFFu)  ? 0.0f : 2.0f);
        p4.z = ((xc >> 22) & 1u) ? 1.0f : (((c31 >> 16) & 0xFFu) ? 0.0f : 2.0f);
        p4.w = ((xc >> 30) & 1u) ? 1.0f : ((c31 >> 24)           ? 0.0f : 2.0f);

        *(float4*)orow = r4;
        *(float4*)prow = p4;
        orow += WW; prow += WW;

        if (i < RPG - 1) {
            const unsigned int xe   = hm[lr + 18][ct];      // e35 row lr0+35+i
            const unsigned int xl31 = hm[lr0 + 2 + i][ct];  // l31 row lr0+2+i
            const unsigned int xe31 = ring_e[i & 1];        // e31 row lr0+33+i
            const unsigned int xl   = ring_l[i & 1];        // l35 row lr0+i
            ring_e[i & 1] = xe;                             // reused at i+2
            ring_l[i & 1] = xl31;                           // reused at i+2
            // per-field: 0 <= value <= 1225+35 < 2^16 (and <=32 < 2^8) -> SWAR-safe
            vA  = (vA + (xe & M6)) - (xl & M6);
            vB  = (vB + ((xe >> 8) & M6)) - ((xl >> 8) & M6);
            c31 = (c31 + ((xe31 >> 7) & M1)) - ((xl31 >> 7) & M1);
        }
    }
}

extern "C" void kernel_launch(void* const* d_in, const int* in_sizes, int n_in,
                              void* d_out, int out_size, void* d_ws, size_t ws_size,
                              hipStream_t stream) {
    const float* masks = (const float*)d_in[0];
    float* out = (float*)d_out;
    dim3 grid(HH / TYO, BATCH);    // 16 x 32 = 512 blocks, 2 per CU
    label_gen_fused<<<grid, NT, 0, stream>>>(masks, out);
}